// Round 3
// baseline (1363.411 us; speedup 1.0000x reference)
//
#include <hip/hip_runtime.h>

#define NN 100000
#define DEG 16
#define HEADS 4
#define NEG_SLOPE 0.2f

// ---------------- GEMM: C[M,Nc] = A[M,K] * W[K,Nc], fp32, row-major ----------
#define BM 64
#define BN 64
#define BK 32

__global__ __launch_bounds__(256) void gemm_f32(
    const float* __restrict__ A, const float* __restrict__ W,
    float* __restrict__ C, int M, int K, int Nc)
{
    __shared__ float As[BK][BM + 1];   // transposed, padded
    __shared__ float Bs[BK][BN];

    const int tid = threadIdx.x;            // 256 threads
    const int tx = tid & 15;                // 0..15 -> col group
    const int ty = tid >> 4;                // 0..15 -> row group
    const int row0 = blockIdx.y * BM;
    const int col0 = blockIdx.x * BN;

    float acc[4][4] = {};

    for (int k0 = 0; k0 < K; k0 += BK) {
        #pragma unroll
        for (int p = 0; p < 2; ++p) {
            int r = p * 32 + (tid >> 3);        // 0..63
            int c = (tid & 7) * 4;              // 0..28
            float4 v = make_float4(0.f, 0.f, 0.f, 0.f);
            int gr = row0 + r;
            if (gr < M)
                v = *reinterpret_cast<const float4*>(&A[(size_t)gr * K + k0 + c]);
            As[c + 0][r] = v.x;
            As[c + 1][r] = v.y;
            As[c + 2][r] = v.z;
            As[c + 3][r] = v.w;
        }
        #pragma unroll
        for (int p = 0; p < 2; ++p) {
            int r = p * 16 + (tid >> 4);        // 0..31
            int c = (tid & 15) * 4;             // 0..60
            float4 v = make_float4(0.f, 0.f, 0.f, 0.f);
            if (col0 + c < Nc)
                v = *reinterpret_cast<const float4*>(&W[(size_t)(k0 + r) * Nc + col0 + c]);
            *reinterpret_cast<float4*>(&Bs[r][c]) = v;
        }
        __syncthreads();

        #pragma unroll
        for (int k = 0; k < BK; ++k) {
            float a[4];
            #pragma unroll
            for (int i = 0; i < 4; ++i) a[i] = As[k][ty * 4 + i];
            float4 bv = *reinterpret_cast<const float4*>(&Bs[k][tx * 4]);
            float b[4] = {bv.x, bv.y, bv.z, bv.w};
            #pragma unroll
            for (int i = 0; i < 4; ++i)
                #pragma unroll
                for (int j = 0; j < 4; ++j)
                    acc[i][j] += a[i] * b[j];
        }
        __syncthreads();
    }

    const int gc0 = col0 + tx * 4;
    #pragma unroll
    for (int i = 0; i < 4; ++i) {
        int gr = row0 + ty * 4 + i;
        if (gr < M && gc0 < Nc) {
            float4 st = make_float4(acc[i][0], acc[i][1], acc[i][2], acc[i][3]);
            *reinterpret_cast<float4*>(&C[(size_t)gr * Nc + gc0]) = st;
        }
    }
}

// ---------------- scores: el[n,h] = sum_d feat[n,h*D+d]*al[h*D+d] ------------
// (proven-correct R1 version, one block per node, wave per head)
__global__ __launch_bounds__(256) void scores_kernel(
    const float* __restrict__ feat, const float* __restrict__ al,
    const float* __restrict__ ar, float* __restrict__ el, float* __restrict__ er,
    int D, int HD)
{
    const int n = blockIdx.x;
    const int t = threadIdx.x;
    const int h = t >> 6;
    const int j = t & 63;
    float v = 0.f, u = 0.f;
    if (j < D) {
        float f = feat[(size_t)n * HD + h * D + j];
        v = f * al[h * D + j];
        u = f * ar[h * D + j];
    }
    #pragma unroll
    for (int off = 32; off > 0; off >>= 1) {
        v += __shfl_down(v, off);
        u += __shfl_down(u, off);
    }
    if (j == 0) {
        el[n * HEADS + h] = v;
        er[n * HEADS + h] = u;
    }
}

// ---------------- aggregation (HD=256): wave per node, LDS-published alpha --
__global__ __launch_bounds__(256) void agg_full_v3(
    const float* __restrict__ feat, const float* __restrict__ el,
    const float* __restrict__ er, const int* __restrict__ col,
    float* __restrict__ out)
{
    __shared__ int   s_src[4][DEG];
    __shared__ float s_alpha[4][HEADS][DEG];

    const int t = threadIdx.x;
    const int w = t >> 6;           // wave -> node slot
    const int l = t & 63;
    const int n = blockIdx.x * 4 + w;
    const int h = l >> 4;           // head
    const int k = l & 15;           // edge slot

    const int src_k = col[n * DEG + k];
    float x = el[src_k * HEADS + h] + er[n * HEADS + h];
    x = x > 0.f ? x : NEG_SLOPE * x;

    // softmax over the 16-lane group (one head)
    float m = x;
    #pragma unroll
    for (int msk = 8; msk >= 1; msk >>= 1) m = fmaxf(m, __shfl_xor(m, msk));
    float ex = __expf(x - m);
    float s = ex;
    #pragma unroll
    for (int msk = 8; msk >= 1; msk >>= 1) s += __shfl_xor(s, msk);

    s_alpha[w][h][k] = ex / s;      // each lane writes its (w,h,k)
    if (l < DEG) s_src[w][l] = src_k;
    __syncthreads();

    // gather: lane l owns output cols 4l..4l+3 (head = l>>4)
    float4 acc = make_float4(0.f, 0.f, 0.f, 0.f);
    #pragma unroll
    for (int k2 = 0; k2 < DEG; ++k2) {
        const int   sk = s_src[w][k2];
        const float a  = s_alpha[w][h][k2];
        float4 f = *reinterpret_cast<const float4*>(&feat[(size_t)sk * 256 + l * 4]);
        acc.x += a * f.x; acc.y += a * f.y; acc.z += a * f.z; acc.w += a * f.w;
    }
    *reinterpret_cast<float4*>(&out[(size_t)n * 256 + l * 4]) = acc;
}

// ---------------- aggregation output layer (HD=164, mean over heads) --------
__global__ __launch_bounds__(256) void agg_out_v3(
    const float* __restrict__ feat, const float* __restrict__ el,
    const float* __restrict__ er, const int* __restrict__ col,
    float* __restrict__ out)   // out: [N, 41]
{
    __shared__ int   s_src[4][DEG];
    __shared__ float s_alpha[4][HEADS][DEG];
    __shared__ float s_agg[4][164];

    const int t = threadIdx.x;
    const int w = t >> 6;
    const int l = t & 63;
    const int n = blockIdx.x * 4 + w;
    const int h = l >> 4;
    const int k = l & 15;

    const int src_k = col[n * DEG + k];
    float x = el[src_k * HEADS + h] + er[n * HEADS + h];
    x = x > 0.f ? x : NEG_SLOPE * x;

    float m = x;
    #pragma unroll
    for (int msk = 8; msk >= 1; msk >>= 1) m = fmaxf(m, __shfl_xor(m, msk));
    float ex = __expf(x - m);
    float s = ex;
    #pragma unroll
    for (int msk = 8; msk >= 1; msk >>= 1) s += __shfl_xor(s, msk);

    s_alpha[w][h][k] = ex / s;
    if (l < DEG) s_src[w][l] = src_k;
    __syncthreads();

    // gather: lanes 0..40 own cols 4l..4l+3 of the 164-wide feat row
    const int l41 = l < 41 ? l : 40;         // clamp keeps loads in-bounds
    const int c0 = 4 * l41;
    const int h0 = (c0 + 0) / 41, h1 = (c0 + 1) / 41;
    const int h2 = (c0 + 2) / 41, h3 = (c0 + 3) / 41;

    float4 acc = make_float4(0.f, 0.f, 0.f, 0.f);
    #pragma unroll
    for (int k2 = 0; k2 < DEG; ++k2) {
        const int sk = s_src[w][k2];
        float4 f = *reinterpret_cast<const float4*>(&feat[(size_t)sk * 164 + c0]);
        acc.x += s_alpha[w][h0][k2] * f.x;
        acc.y += s_alpha[w][h1][k2] * f.y;
        acc.z += s_alpha[w][h2][k2] * f.z;
        acc.w += s_alpha[w][h3][k2] * f.w;
    }
    if (l < 41) *reinterpret_cast<float4*>(&s_agg[w][c0]) = acc;
    __syncthreads();
    if (l < 41)
        out[(size_t)n * 41 + l] =
            0.25f * (s_agg[w][l] + s_agg[w][l + 41] + s_agg[w][l + 82] + s_agg[w][l + 123]);
}

extern "C" void kernel_launch(void* const* d_in, const int* in_sizes, int n_in,
                              void* d_out, int out_size, void* d_ws, size_t ws_size,
                              hipStream_t stream)
{
    const int*   col_ind = (const int*)  d_in[1];
    const float* inputs  = (const float*)d_in[2];
    const float* W0      = (const float*)d_in[3];
    const float* al0     = (const float*)d_in[4];
    const float* ar0     = (const float*)d_in[5];
    const float* W1      = (const float*)d_in[6];
    const float* al1     = (const float*)d_in[7];
    const float* ar1     = (const float*)d_in[8];
    const float* W2      = (const float*)d_in[9];
    const float* al2     = (const float*)d_in[10];
    const float* ar2     = (const float*)d_in[11];
    float* out = (float*)d_out;

    char* ws = (char*)d_ws;
    const size_t featBytes = (size_t)NN * 256 * sizeof(float);
    float* featA = (float*)ws;
    float* hB    = (float*)(ws + featBytes);
    float* el    = (float*)(ws + 2 * featBytes);
    float* er    = el + (size_t)NN * HEADS;

    dim3 blk(256);
    dim3 g256(4, (NN + BM - 1) / BM);
    dim3 g164(3, (NN + BM - 1) / BM);
    const int waveGrid = NN / 4;   // 25000 blocks, 4 nodes (1 wave each)

    // Layer 0
    gemm_f32<<<g256, blk, 0, stream>>>(inputs, W0, featA, NN, 256, 256);
    scores_kernel<<<NN, blk, 0, stream>>>(featA, al0, ar0, el, er, 64, 256);
    agg_full_v3<<<waveGrid, blk, 0, stream>>>(featA, el, er, col_ind, hB);

    // Layer 1
    gemm_f32<<<g256, blk, 0, stream>>>(hB, W1, featA, NN, 256, 256);
    scores_kernel<<<NN, blk, 0, stream>>>(featA, al1, ar1, el, er, 64, 256);
    agg_full_v3<<<waveGrid, blk, 0, stream>>>(featA, el, er, col_ind, hB);

    // Layer 2
    gemm_f32<<<g164, blk, 0, stream>>>(hB, W2, featA, NN, 256, 164);
    scores_kernel<<<NN, blk, 0, stream>>>(featA, al2, ar2, el, er, 41, 164);
    agg_out_v3<<<waveGrid, blk, 0, stream>>>(featA, el, er, col_ind, out);
}

// Round 4
// 953.968 us; speedup vs baseline: 1.4292x; 1.4292x over previous
//
#include <hip/hip_runtime.h>

#define NN 100000
#define DEG 16
#define HEADS 4
#define NEG_SLOPE 0.2f

typedef unsigned short ushort_t;

__device__ __forceinline__ ushort_t f2bf(float f) {
    uint32_t u = __float_as_uint(f);
    uint32_t r = (u + 0x7fffu + ((u >> 16) & 1u)) >> 16;
    return (ushort_t)r;
}
__device__ __forceinline__ float bf2f(ushort_t u) {
    return __uint_as_float(((uint32_t)u) << 16);
}

// ---- GEMM: C_bf16[M,Nc] = A[M,K] * W[K,Nc]; optional fused el/er scores ----
#define BM 64
#define BN 64
#define BK 32

template <bool DO_SCORES>
__global__ __launch_bounds__(256) void gemm_fused(
    const float* __restrict__ A, const float* __restrict__ W,
    const float* __restrict__ al, const float* __restrict__ ar,
    ushort_t* __restrict__ Cb, float* __restrict__ el, float* __restrict__ er,
    int M, int K, int Nc)
{
    __shared__ float As[BK][BM + 1];
    __shared__ float Bs[BK][BN];
    __shared__ float s_el[BM][16];
    __shared__ float s_er[BM][16];

    const int tid = threadIdx.x;
    const int tx = tid & 15;
    const int ty = tid >> 4;
    const int row0 = blockIdx.y * BM;
    const int col0 = blockIdx.x * BN;

    float acc[4][4] = {};

    for (int k0 = 0; k0 < K; k0 += BK) {
        #pragma unroll
        for (int p = 0; p < 2; ++p) {
            int r = p * 32 + (tid >> 3);
            int c = (tid & 7) * 4;
            float4 v = make_float4(0.f, 0.f, 0.f, 0.f);
            int gr = row0 + r;
            if (gr < M)
                v = *reinterpret_cast<const float4*>(&A[(size_t)gr * K + k0 + c]);
            As[c + 0][r] = v.x;
            As[c + 1][r] = v.y;
            As[c + 2][r] = v.z;
            As[c + 3][r] = v.w;
        }
        #pragma unroll
        for (int p = 0; p < 2; ++p) {
            int r = p * 16 + (tid >> 4);
            int c = (tid & 15) * 4;
            float4 v = make_float4(0.f, 0.f, 0.f, 0.f);
            if (col0 + c < Nc)
                v = *reinterpret_cast<const float4*>(&W[(size_t)(k0 + r) * Nc + col0 + c]);
            *reinterpret_cast<float4*>(&Bs[r][c]) = v;
        }
        __syncthreads();

        #pragma unroll
        for (int k = 0; k < BK; ++k) {
            float a[4];
            #pragma unroll
            for (int i = 0; i < 4; ++i) a[i] = As[k][ty * 4 + i];
            float4 bv = *reinterpret_cast<const float4*>(&Bs[k][tx * 4]);
            float b[4] = {bv.x, bv.y, bv.z, bv.w};
            #pragma unroll
            for (int i = 0; i < 4; ++i)
                #pragma unroll
                for (int j = 0; j < 4; ++j)
                    acc[i][j] += a[i] * b[j];
        }
        __syncthreads();
    }

    // Store bf16 output (8 B per row-chunk)
    const int gc0 = col0 + tx * 4;
    #pragma unroll
    for (int i = 0; i < 4; ++i) {
        int gr = row0 + ty * 4 + i;
        if (gr < M && gc0 < Nc) {
            ushort4 st;
            st.x = f2bf(acc[i][0]); st.y = f2bf(acc[i][1]);
            st.z = f2bf(acc[i][2]); st.w = f2bf(acc[i][3]);
            *reinterpret_cast<ushort4*>(&Cb[(size_t)gr * Nc + gc0]) = st;
        }
    }

    if (DO_SCORES) {
        // This block's 64 cols == head h (Nc=256, BN=64 aligned)
        const int h = col0 >> 6;
        float pl = 0.f, pr = 0.f;
        #pragma unroll
        for (int j = 0; j < 4; ++j) {
            // same al value for all rows of this thread's column j
            float av = al[col0 + tx * 4 + j];
            float rv = ar[col0 + tx * 4 + j];
            (void)av; (void)rv;
        }
        // per-row partials: accumulate into LDS per (row, tx)
        #pragma unroll
        for (int i = 0; i < 4; ++i) {
            pl = 0.f; pr = 0.f;
            #pragma unroll
            for (int j = 0; j < 4; ++j) {
                float av = al[col0 + tx * 4 + j];
                float rv = ar[col0 + tx * 4 + j];
                pl += acc[i][j] * av;
                pr += acc[i][j] * rv;
            }
            s_el[ty * 4 + i][tx] = pl;
            s_er[ty * 4 + i][tx] = pr;
        }
        __syncthreads();
        if (tid < BM) {
            int gr = row0 + tid;
            if (gr < M) {
                float sl = 0.f, sr = 0.f;
                #pragma unroll
                for (int x = 0; x < 16; ++x) { sl += s_el[tid][x]; sr += s_er[tid][x]; }
                el[gr * HEADS + h] = sl;
                er[gr * HEADS + h] = sr;
            }
        }
    }
}

// ---- layer-2 scores from bf16 feat (D=41, HD=164) --------------------------
__global__ __launch_bounds__(256) void scores2_bf(
    const ushort_t* __restrict__ featb, const float* __restrict__ al,
    const float* __restrict__ ar, float* __restrict__ el, float* __restrict__ er)
{
    const int n = blockIdx.x;
    const int t = threadIdx.x;
    const int h = t >> 6;
    const int j = t & 63;
    float v = 0.f, u = 0.f;
    if (j < 41) {
        float f = bf2f(featb[(size_t)n * 164 + h * 41 + j]);
        v = f * al[h * 41 + j];
        u = f * ar[h * 41 + j];
    }
    #pragma unroll
    for (int off = 32; off > 0; off >>= 1) {
        v += __shfl_down(v, off);
        u += __shfl_down(u, off);
    }
    if (j == 0) {
        el[n * HEADS + h] = v;
        er[n * HEADS + h] = u;
    }
}

// ---- aggregation (HD=256) from bf16 rows: wave per node --------------------
__global__ __launch_bounds__(256) void agg_full_bf(
    const ushort_t* __restrict__ featb, const float* __restrict__ el,
    const float* __restrict__ er, const int* __restrict__ col,
    float* __restrict__ out)
{
    __shared__ int   s_src[4][DEG];
    __shared__ float s_alpha[4][HEADS][DEG];

    const int t = threadIdx.x;
    const int w = t >> 6;
    const int l = t & 63;
    const int n = blockIdx.x * 4 + w;
    const int h = l >> 4;
    const int k = l & 15;

    const int src_k = col[n * DEG + k];
    float x = el[src_k * HEADS + h] + er[n * HEADS + h];
    x = x > 0.f ? x : NEG_SLOPE * x;

    float m = x;
    #pragma unroll
    for (int msk = 8; msk >= 1; msk >>= 1) m = fmaxf(m, __shfl_xor(m, msk));
    float ex = __expf(x - m);
    float s = ex;
    #pragma unroll
    for (int msk = 8; msk >= 1; msk >>= 1) s += __shfl_xor(s, msk);

    s_alpha[w][h][k] = ex / s;
    if (l < DEG) s_src[w][l] = src_k;
    __syncthreads();

    float4 acc = make_float4(0.f, 0.f, 0.f, 0.f);
    #pragma unroll
    for (int k2 = 0; k2 < DEG; ++k2) {
        const int   sk = s_src[w][k2];
        const float a  = s_alpha[w][h][k2];
        ushort4 f = *reinterpret_cast<const ushort4*>(&featb[(size_t)sk * 256 + l * 4]);
        acc.x += a * bf2f(f.x);
        acc.y += a * bf2f(f.y);
        acc.z += a * bf2f(f.z);
        acc.w += a * bf2f(f.w);
    }
    *reinterpret_cast<float4*>(&out[(size_t)n * 256 + l * 4]) = acc;
}

// ---- output-layer aggregation (HD=164, mean over heads) from bf16 ----------
__global__ __launch_bounds__(256) void agg_out_bf(
    const ushort_t* __restrict__ featb, const float* __restrict__ el,
    const float* __restrict__ er, const int* __restrict__ col,
    float* __restrict__ out)   // out: [N, 41]
{
    __shared__ int   s_src[4][DEG];
    __shared__ float s_alpha[4][HEADS][DEG];
    __shared__ float s_agg[4][164];

    const int t = threadIdx.x;
    const int w = t >> 6;
    const int l = t & 63;
    const int n = blockIdx.x * 4 + w;
    const int h = l >> 4;
    const int k = l & 15;

    const int src_k = col[n * DEG + k];
    float x = el[src_k * HEADS + h] + er[n * HEADS + h];
    x = x > 0.f ? x : NEG_SLOPE * x;

    float m = x;
    #pragma unroll
    for (int msk = 8; msk >= 1; msk >>= 1) m = fmaxf(m, __shfl_xor(m, msk));
    float ex = __expf(x - m);
    float s = ex;
    #pragma unroll
    for (int msk = 8; msk >= 1; msk >>= 1) s += __shfl_xor(s, msk);

    s_alpha[w][h][k] = ex / s;
    if (l < DEG) s_src[w][l] = src_k;
    __syncthreads();

    const int l41 = l < 41 ? l : 40;
    const int c0 = 4 * l41;
    const int h0 = (c0 + 0) / 41, h1 = (c0 + 1) / 41;
    const int h2 = (c0 + 2) / 41, h3 = (c0 + 3) / 41;

    float4 acc = make_float4(0.f, 0.f, 0.f, 0.f);
    #pragma unroll
    for (int k2 = 0; k2 < DEG; ++k2) {
        const int sk = s_src[w][k2];
        ushort4 f = *reinterpret_cast<const ushort4*>(&featb[(size_t)sk * 164 + c0]);
        acc.x += s_alpha[w][h0][k2] * bf2f(f.x);
        acc.y += s_alpha[w][h1][k2] * bf2f(f.y);
        acc.z += s_alpha[w][h2][k2] * bf2f(f.z);
        acc.w += s_alpha[w][h3][k2] * bf2f(f.w);
    }
    if (l < 41) *reinterpret_cast<float4*>(&s_agg[w][c0]) = acc;
    __syncthreads();
    if (l < 41)
        out[(size_t)n * 41 + l] =
            0.25f * (s_agg[w][l] + s_agg[w][l + 41] + s_agg[w][l + 82] + s_agg[w][l + 123]);
}

extern "C" void kernel_launch(void* const* d_in, const int* in_sizes, int n_in,
                              void* d_out, int out_size, void* d_ws, size_t ws_size,
                              hipStream_t stream)
{
    const int*   col_ind = (const int*)  d_in[1];
    const float* inputs  = (const float*)d_in[2];
    const float* W0      = (const float*)d_in[3];
    const float* al0     = (const float*)d_in[4];
    const float* ar0     = (const float*)d_in[5];
    const float* W1      = (const float*)d_in[6];
    const float* al1     = (const float*)d_in[7];
    const float* ar1     = (const float*)d_in[8];
    const float* W2      = (const float*)d_in[9];
    const float* al2     = (const float*)d_in[10];
    const float* ar2     = (const float*)d_in[11];
    float* out = (float*)d_out;

    char* ws = (char*)d_ws;
    float*    h     = (float*)ws;                                   // [N,256] fp32
    ushort_t* featb = (ushort_t*)(ws + (size_t)NN * 256 * 4);       // [N,256] bf16
    float*    el    = (float*)(ws + (size_t)NN * 256 * 4 + (size_t)NN * 256 * 2);
    float*    er    = el + (size_t)NN * HEADS;

    dim3 blk(256);
    dim3 g256(4, (NN + BM - 1) / BM);
    dim3 g164(3, (NN + BM - 1) / BM);
    const int waveGrid = NN / 4;

    // Layer 0: GEMM (+fused scores, bf16 out) -> agg
    gemm_fused<true><<<g256, blk, 0, stream>>>(inputs, W0, al0, ar0,
                                               featb, el, er, NN, 256, 256);
    agg_full_bf<<<waveGrid, blk, 0, stream>>>(featb, el, er, col_ind, h);

    // Layer 1
    gemm_fused<true><<<g256, blk, 0, stream>>>(h, W1, al1, ar1,
                                               featb, el, er, NN, 256, 256);
    agg_full_bf<<<waveGrid, blk, 0, stream>>>(featb, el, er, col_ind, h);

    // Layer 2: GEMM (bf16 out, no fused scores) -> scores -> agg+mean
    gemm_fused<false><<<g164, blk, 0, stream>>>(h, W2, nullptr, nullptr,
                                                featb, nullptr, nullptr, NN, 256, 164);
    scores2_bf<<<NN, blk, 0, stream>>>(featb, al2, ar2, el, er);
    agg_out_bf<<<waveGrid, blk, 0, stream>>>(featb, el, er, col_ind, out);
}

// Round 5
// 752.206 us; speedup vs baseline: 1.8126x; 1.2682x over previous
//
#include <hip/hip_runtime.h>

#define NN 100000
#define DEG 16
#define HEADS 4
#define NEG_SLOPE 0.2f
#define NPAD 100096   // 782 * 128

typedef unsigned short ushort_t;
typedef __attribute__((ext_vector_type(8))) short bf16x8;
typedef __attribute__((ext_vector_type(4))) float f32x4;

__device__ __forceinline__ ushort_t f2bf_rn(float f) {
    uint32_t u = __float_as_uint(f);
    uint32_t r = (u + 0x7fffu + ((u >> 16) & 1u)) >> 16;
    return (ushort_t)r;
}
__device__ __forceinline__ float bf2f(ushort_t u) {
    return __uint_as_float(((uint32_t)u) << 16);
}

// ---- prep: Wt_hi/lo[n][k] = split(W[k][n]), n padded to 256 with zeros -----
__global__ __launch_bounds__(256) void prep_wt(
    const float* __restrict__ W, ushort_t* __restrict__ Wh,
    ushort_t* __restrict__ Wl, int ncr)
{
    int idx = blockIdx.x * 256 + threadIdx.x;   // 65536 = [n][k]
    int n = idx >> 8, k = idx & 255;
    float v = (n < ncr) ? W[k * ncr + n] : 0.f;
    uint32_t b  = __float_as_uint(v);
    uint32_t hb = b & 0xffff0000u;
    float r = v - __uint_as_float(hb);
    Wh[idx] = (ushort_t)(hb >> 16);
    Wl[idx] = (ushort_t)(__float_as_uint(r) >> 16);
}

// ---- split-bf16 MFMA GEMM: C[M,256pad] = A[M,256] * W[256,256pad] ----------
// AMODE 0: A = fp32 A32[NN][256] (layer 0).  AMODE 1: A = Ahi/Alo presplit.
// Stores bf16 C (cols < ncr, stride ldc); DO_SCORES fuses el/er from fp32 acc.
template <int AMODE, bool DO_SCORES>
__global__ __launch_bounds__(256) void gemm_mfma(
    const float* __restrict__ A32,
    const ushort_t* __restrict__ Ahi, const ushort_t* __restrict__ Alo,
    const ushort_t* __restrict__ Bth, const ushort_t* __restrict__ Btl, // [256][256]
    const float* __restrict__ al, const float* __restrict__ ar,
    ushort_t* __restrict__ Cb, int ldc, int ncr,
    float* __restrict__ el, float* __restrict__ er)
{
    __shared__ uint4 smem[2048];   // 32 KB: [0:1024) a_hi, [1024:2048) a_lo

    const int tid  = threadIdx.x;
    const int wv   = tid >> 6;
    const int ln   = tid & 63;
    const int wm   = wv >> 1;          // 0..1 row-wave
    const int wn   = wv & 1;           // 0..1 col-wave
    const int cl   = ln & 15;
    const int kq   = ln >> 4;          // 0..3
    const int row0 = blockIdx.y * 128;
    const int col0 = blockIdx.x * 128;

    f32x4 acc[4][4] = {};

    for (int k0 = 0; k0 < 256; k0 += 64) {
        if (k0) __syncthreads();
        // ---- stage A tile [128 rows][64 k] as hi/lo bf16, XOR-swizzled ----
        if (AMODE == 1) {
            #pragma unroll
            for (int p = 0; p < 4; ++p) {
                int s = p * 256 + tid;
                int row = s >> 3, c = s & 7;
                int csw = c ^ (row & 7);
                size_t g = (size_t)(row0 + row) * 256 + k0 + c * 8;
                smem[row * 8 + csw]        = *reinterpret_cast<const uint4*>(Ahi + g);
                smem[1024 + row * 8 + csw] = *reinterpret_cast<const uint4*>(Alo + g);
            }
        } else {
            #pragma unroll
            for (int p = 0; p < 4; ++p) {
                int s = p * 256 + tid;
                int row = s >> 3, c = s & 7;
                int csw = c ^ (row & 7);
                int gr = row0 + row;
                float4 v0 = make_float4(0.f,0.f,0.f,0.f), v1 = v0;
                if (gr < NN) {
                    const float* g = A32 + (size_t)gr * 256 + k0 + c * 8;
                    v0 = *reinterpret_cast<const float4*>(g);
                    v1 = *reinterpret_cast<const float4*>(g + 4);
                }
                uint32_t b0 = __float_as_uint(v0.x), b1 = __float_as_uint(v0.y);
                uint32_t b2 = __float_as_uint(v0.z), b3 = __float_as_uint(v0.w);
                uint32_t b4 = __float_as_uint(v1.x), b5 = __float_as_uint(v1.y);
                uint32_t b6 = __float_as_uint(v1.z), b7 = __float_as_uint(v1.w);
                uint4 vh;
                vh.x = (b1 & 0xffff0000u) | (b0 >> 16);
                vh.y = (b3 & 0xffff0000u) | (b2 >> 16);
                vh.z = (b5 & 0xffff0000u) | (b4 >> 16);
                vh.w = (b7 & 0xffff0000u) | (b6 >> 16);
                float r0 = v0.x - __uint_as_float(b0 & 0xffff0000u);
                float r1 = v0.y - __uint_as_float(b1 & 0xffff0000u);
                float r2 = v0.z - __uint_as_float(b2 & 0xffff0000u);
                float r3 = v0.w - __uint_as_float(b3 & 0xffff0000u);
                float r4 = v1.x - __uint_as_float(b4 & 0xffff0000u);
                float r5 = v1.y - __uint_as_float(b5 & 0xffff0000u);
                float r6 = v1.z - __uint_as_float(b6 & 0xffff0000u);
                float r7 = v1.w - __uint_as_float(b7 & 0xffff0000u);
                uint4 vl;
                vl.x = (__float_as_uint(r1) & 0xffff0000u) | (__float_as_uint(r0) >> 16);
                vl.y = (__float_as_uint(r3) & 0xffff0000u) | (__float_as_uint(r2) >> 16);
                vl.z = (__float_as_uint(r5) & 0xffff0000u) | (__float_as_uint(r4) >> 16);
                vl.w = (__float_as_uint(r7) & 0xffff0000u) | (__float_as_uint(r6) >> 16);
                smem[row * 8 + csw]        = vh;
                smem[1024 + row * 8 + csw] = vl;
            }
        }
        __syncthreads();

        // ---- compute: 2 ksub windows of K=32 -----------------------------
        #pragma unroll
        for (int ksub = 0; ksub < 2; ++ksub) {
            bf16x8 ah[4], ax[4];
            #pragma unroll
            for (int mf = 0; mf < 4; ++mf) {
                int row = wm * 64 + mf * 16 + cl;
                int chunk = (ksub * 4 + kq) ^ (row & 7);
                int idx = row * 8 + chunk;
                ah[mf] = ((const bf16x8*)smem)[idx];
                ax[mf] = ((const bf16x8*)smem)[1024 + idx];
            }
            #pragma unroll
            for (int nf = 0; nf < 4; ++nf) {
                int colg = col0 + wn * 64 + nf * 16 + cl;
                size_t boff = (size_t)colg * 256 + k0 + ksub * 32 + kq * 8;
                bf16x8 bh = *reinterpret_cast<const bf16x8*>(Bth + boff);
                bf16x8 bl = *reinterpret_cast<const bf16x8*>(Btl + boff);
                #pragma unroll
                for (int mf = 0; mf < 4; ++mf) {
                    acc[mf][nf] = __builtin_amdgcn_mfma_f32_16x16x32_bf16(ah[mf], bh, acc[mf][nf], 0, 0, 0);
                    acc[mf][nf] = __builtin_amdgcn_mfma_f32_16x16x32_bf16(ah[mf], bl, acc[mf][nf], 0, 0, 0);
                    acc[mf][nf] = __builtin_amdgcn_mfma_f32_16x16x32_bf16(ax[mf], bh, acc[mf][nf], 0, 0, 0);
                }
            }
        }
    }

    // ---- epilogue: bf16 C store (+ fused scores) -------------------------
    #pragma unroll
    for (int mf = 0; mf < 4; ++mf) {
        int gr0 = row0 + wm * 64 + mf * 16 + kq * 4;
        #pragma unroll
        for (int r = 0; r < 4; ++r) {
            int gr = gr0 + r;
            if (gr < NN) {
                #pragma unroll
                for (int nf = 0; nf < 4; ++nf) {
                    int gc = col0 + wn * 64 + nf * 16 + cl;
                    if (gc < ncr)
                        Cb[(size_t)gr * ldc + gc] = f2bf_rn(acc[mf][nf][r]);
                }
            }
        }
    }

    if (DO_SCORES) {
        const int head = blockIdx.x * 2 + wn;
        float alv[4], arv[4];
        #pragma unroll
        for (int nf = 0; nf < 4; ++nf) {
            int d = nf * 16 + cl;
            alv[nf] = al[head * 64 + d];
            arv[nf] = ar[head * 64 + d];
        }
        #pragma unroll
        for (int mf = 0; mf < 4; ++mf) {
            #pragma unroll
            for (int r = 0; r < 4; ++r) {
                float pl = 0.f, pr = 0.f;
                #pragma unroll
                for (int nf = 0; nf < 4; ++nf) {
                    pl += acc[mf][nf][r] * alv[nf];
                    pr += acc[mf][nf][r] * arv[nf];
                }
                #pragma unroll
                for (int msk = 1; msk <= 8; msk <<= 1) {
                    pl += __shfl_xor(pl, msk);
                    pr += __shfl_xor(pr, msk);
                }
                if (cl == 0) {
                    int gr = row0 + wm * 64 + mf * 16 + kq * 4 + r;
                    if (gr < NN) {
                        el[gr * HEADS + head] = pl;
                        er[gr * HEADS + head] = pr;
                    }
                }
            }
        }
    }
}

// ---- layer-2 scores from bf16 feat (D=41, HD=164) --------------------------
__global__ __launch_bounds__(256) void scores2_bf(
    const ushort_t* __restrict__ featb, const float* __restrict__ al,
    const float* __restrict__ ar, float* __restrict__ el, float* __restrict__ er)
{
    const int n = blockIdx.x;
    const int t = threadIdx.x;
    const int h = t >> 6;
    const int j = t & 63;
    float v = 0.f, u = 0.f;
    if (j < 41) {
        float f = bf2f(featb[(size_t)n * 164 + h * 41 + j]);
        v = f * al[h * 41 + j];
        u = f * ar[h * 41 + j];
    }
    #pragma unroll
    for (int off = 32; off > 0; off >>= 1) {
        v += __shfl_down(v, off);
        u += __shfl_down(u, off);
    }
    if (j == 0) {
        el[n * HEADS + h] = v;
        er[n * HEADS + h] = u;
    }
}

// ---- aggregation (HD=256): wave per node; writes h as hi/lo split ----------
__global__ __launch_bounds__(256) void agg_full_bf(
    const ushort_t* __restrict__ featb, const float* __restrict__ el,
    const float* __restrict__ er, const int* __restrict__ col,
    ushort_t* __restrict__ Hhi, ushort_t* __restrict__ Hlo)
{
    __shared__ int   s_src[4][DEG];
    __shared__ float s_alpha[4][HEADS][DEG];

    const int t = threadIdx.x;
    const int w = t >> 6;
    const int l = t & 63;
    const int n = blockIdx.x * 4 + w;
    const int h = l >> 4;
    const int k = l & 15;

    const int src_k = col[n * DEG + k];
    float x = el[src_k * HEADS + h] + er[n * HEADS + h];
    x = x > 0.f ? x : NEG_SLOPE * x;

    float m = x;
    #pragma unroll
    for (int msk = 8; msk >= 1; msk >>= 1) m = fmaxf(m, __shfl_xor(m, msk));
    float ex = __expf(x - m);
    float s = ex;
    #pragma unroll
    for (int msk = 8; msk >= 1; msk >>= 1) s += __shfl_xor(s, msk);

    s_alpha[w][h][k] = ex / s;
    if (l < DEG) s_src[w][l] = src_k;
    __syncthreads();

    float4 acc = make_float4(0.f, 0.f, 0.f, 0.f);
    #pragma unroll
    for (int k2 = 0; k2 < DEG; ++k2) {
        const int   sk = s_src[w][k2];
        const float a  = s_alpha[w][h][k2];
        ushort4 f = *reinterpret_cast<const ushort4*>(&featb[(size_t)sk * 256 + l * 4]);
        acc.x += a * bf2f(f.x);
        acc.y += a * bf2f(f.y);
        acc.z += a * bf2f(f.z);
        acc.w += a * bf2f(f.w);
    }
    uint32_t bx = __float_as_uint(acc.x), by = __float_as_uint(acc.y);
    uint32_t bz = __float_as_uint(acc.z), bw = __float_as_uint(acc.w);
    ushort4 hv;
    hv.x = (ushort_t)(bx >> 16); hv.y = (ushort_t)(by >> 16);
    hv.z = (ushort_t)(bz >> 16); hv.w = (ushort_t)(bw >> 16);
    float rx = acc.x - __uint_as_float(bx & 0xffff0000u);
    float ry = acc.y - __uint_as_float(by & 0xffff0000u);
    float rz = acc.z - __uint_as_float(bz & 0xffff0000u);
    float rw = acc.w - __uint_as_float(bw & 0xffff0000u);
    ushort4 lv;
    lv.x = (ushort_t)(__float_as_uint(rx) >> 16);
    lv.y = (ushort_t)(__float_as_uint(ry) >> 16);
    lv.z = (ushort_t)(__float_as_uint(rz) >> 16);
    lv.w = (ushort_t)(__float_as_uint(rw) >> 16);
    *reinterpret_cast<ushort4*>(&Hhi[(size_t)n * 256 + l * 4]) = hv;
    *reinterpret_cast<ushort4*>(&Hlo[(size_t)n * 256 + l * 4]) = lv;
}

// ---- output-layer aggregation (HD=164, mean over heads) --------------------
__global__ __launch_bounds__(256) void agg_out_bf(
    const ushort_t* __restrict__ featb, const float* __restrict__ el,
    const float* __restrict__ er, const int* __restrict__ col,
    float* __restrict__ out)   // out: [N, 41]
{
    __shared__ int   s_src[4][DEG];
    __shared__ float s_alpha[4][HEADS][DEG];
    __shared__ float s_agg[4][164];

    const int t = threadIdx.x;
    const int w = t >> 6;
    const int l = t & 63;
    const int n = blockIdx.x * 4 + w;
    const int h = l >> 4;
    const int k = l & 15;

    const int src_k = col[n * DEG + k];
    float x = el[src_k * HEADS + h] + er[n * HEADS + h];
    x = x > 0.f ? x : NEG_SLOPE * x;

    float m = x;
    #pragma unroll
    for (int msk = 8; msk >= 1; msk >>= 1) m = fmaxf(m, __shfl_xor(m, msk));
    float ex = __expf(x - m);
    float s = ex;
    #pragma unroll
    for (int msk = 8; msk >= 1; msk >>= 1) s += __shfl_xor(s, msk);

    s_alpha[w][h][k] = ex / s;
    if (l < DEG) s_src[w][l] = src_k;
    __syncthreads();

    const int l41 = l < 41 ? l : 40;
    const int c0 = 4 * l41;
    const int h0 = (c0 + 0) / 41, h1 = (c0 + 1) / 41;
    const int h2 = (c0 + 2) / 41, h3 = (c0 + 3) / 41;

    float4 acc = make_float4(0.f, 0.f, 0.f, 0.f);
    #pragma unroll
    for (int k2 = 0; k2 < DEG; ++k2) {
        const int sk = s_src[w][k2];
        ushort4 f = *reinterpret_cast<const ushort4*>(&featb[(size_t)sk * 164 + c0]);
        acc.x += s_alpha[w][h0][k2] * bf2f(f.x);
        acc.y += s_alpha[w][h1][k2] * bf2f(f.y);
        acc.z += s_alpha[w][h2][k2] * bf2f(f.z);
        acc.w += s_alpha[w][h3][k2] * bf2f(f.w);
    }
    if (l < 41) *reinterpret_cast<float4*>(&s_agg[w][c0]) = acc;
    __syncthreads();
    if (l < 41)
        out[(size_t)n * 41 + l] =
            0.25f * (s_agg[w][l] + s_agg[w][l + 41] + s_agg[w][l + 82] + s_agg[w][l + 123]);
}

extern "C" void kernel_launch(void* const* d_in, const int* in_sizes, int n_in,
                              void* d_out, int out_size, void* d_ws, size_t ws_size,
                              hipStream_t stream)
{
    const int*   col_ind = (const int*)  d_in[1];
    const float* inputs  = (const float*)d_in[2];
    const float* W0      = (const float*)d_in[3];
    const float* al0     = (const float*)d_in[4];
    const float* ar0     = (const float*)d_in[5];
    const float* W1      = (const float*)d_in[6];
    const float* al1     = (const float*)d_in[7];
    const float* ar1     = (const float*)d_in[8];
    const float* W2      = (const float*)d_in[9];
    const float* al2     = (const float*)d_in[10];
    const float* ar2     = (const float*)d_in[11];
    float* out = (float*)d_out;

    char* ws = (char*)d_ws;
    const size_t seg = (size_t)NPAD * 256 * sizeof(ushort_t);   // 51.25 MB
    ushort_t* h_hi  = (ushort_t*)(ws);
    ushort_t* h_lo  = (ushort_t*)(ws + seg);
    ushort_t* featb = (ushort_t*)(ws + 2 * seg);
    float*    el    = (float*)(ws + 3 * seg);
    float*    er    = el + (size_t)NN * HEADS;
    ushort_t* wt    = (ushort_t*)(er + (size_t)NN * HEADS);
    ushort_t* wt0h = wt;              ushort_t* wt0l = wt + 65536;
    ushort_t* wt1h = wt + 2 * 65536;  ushort_t* wt1l = wt + 3 * 65536;
    ushort_t* wt2h = wt + 4 * 65536;  ushort_t* wt2l = wt + 5 * 65536;

    dim3 blk(256);
    dim3 gg(2, (NN + 127) / 128);
    const int waveGrid = NN / 4;

    prep_wt<<<256, blk, 0, stream>>>(W0, wt0h, wt0l, 256);
    prep_wt<<<256, blk, 0, stream>>>(W1, wt1h, wt1l, 256);
    prep_wt<<<256, blk, 0, stream>>>(W2, wt2h, wt2l, 164);

    // Layer 0: fp32 A path, fused scores
    gemm_mfma<0, true><<<gg, blk, 0, stream>>>(
        inputs, nullptr, nullptr, wt0h, wt0l, al0, ar0, featb, 256, 256, el, er);
    agg_full_bf<<<waveGrid, blk, 0, stream>>>(featb, el, er, col_ind, h_hi, h_lo);

    // Layer 1: presplit A path, fused scores
    gemm_mfma<1, true><<<gg, blk, 0, stream>>>(
        nullptr, h_hi, h_lo, wt1h, wt1l, al1, ar1, featb, 256, 256, el, er);
    agg_full_bf<<<waveGrid, blk, 0, stream>>>(featb, el, er, col_ind, h_hi, h_lo);

    // Layer 2: presplit A, padded cols, no fused scores
    gemm_mfma<1, false><<<gg, blk, 0, stream>>>(
        nullptr, h_hi, h_lo, wt2h, wt2l, nullptr, nullptr, featb, 164, 164, nullptr, nullptr);
    scores2_bf<<<NN, blk, 0, stream>>>(featb, al2, ar2, el, er);
    agg_out_bf<<<waveGrid, blk, 0, stream>>>(featb, el, er, col_ind, out);
}

// Round 6
// 658.095 us; speedup vs baseline: 2.0718x; 1.1430x over previous
//
#include <hip/hip_runtime.h>

#define NN 100000
#define DEG 16
#define HEADS 4
#define NEG_SLOPE 0.2f
#define NPAD 100096   // 782 * 128

typedef unsigned short ushort_t;
typedef __attribute__((ext_vector_type(8))) short bf16x8;
typedef __attribute__((ext_vector_type(4))) float f32x4;

__device__ __forceinline__ ushort_t f2bf_rn(float f) {
    uint32_t u = __float_as_uint(f);
    uint32_t r = (u + 0x7fffu + ((u >> 16) & 1u)) >> 16;
    return (ushort_t)r;
}
__device__ __forceinline__ float bf2f(ushort_t u) {
    return __uint_as_float(((uint32_t)u) << 16);
}

// ---- prep: W[k][col] -> fragment-linear hi/lo bf16 panels ------------------
// Layout (16B chunks): [p][k0g][wn][ksub][nf][ln], chunk elem j:
//   col = p*128 + wn*64 + nf*16 + (ln&15)
//   k   = k0g*64 + ksub*32 + (ln>>4)*8 + j
__global__ __launch_bounds__(256) void prep_wt(
    const float* __restrict__ W, ushort_t* __restrict__ Wh,
    ushort_t* __restrict__ Wl, int ncr)
{
    int idx = blockIdx.x * 256 + threadIdx.x;   // 65536 elements
    int j     = idx & 7;
    int chunk = idx >> 3;
    int ln   = chunk & 63;
    int nf   = (chunk >> 6) & 3;
    int ksub = (chunk >> 8) & 1;
    int wn   = (chunk >> 9) & 1;
    int k0g  = (chunk >> 10) & 3;
    int p    = (chunk >> 12) & 1;
    int col = p * 128 + wn * 64 + nf * 16 + (ln & 15);
    int k   = k0g * 64 + ksub * 32 + (ln >> 4) * 8 + j;
    float v = (col < ncr) ? W[k * ncr + col] : 0.f;
    uint32_t b  = __float_as_uint(v);
    uint32_t hb = b & 0xffff0000u;
    float r = v - __uint_as_float(hb);
    Wh[idx] = (ushort_t)(hb >> 16);
    Wl[idx] = (ushort_t)(__float_as_uint(r) >> 16);
}

// ---- split-bf16 MFMA GEMM: C[M,256] = A[M,256] * W[256,256] ----------------
// AMODE 0: A = fp32 A32 (layer 0).  AMODE 1: A = Ahi/Alo presplit bf16.
// B comes from fragment-linear Wh/Wl (prep_wt layout), staged in LDS.
template <int AMODE, bool DO_SCORES>
__global__ __launch_bounds__(256) void gemm_mfma(
    const float* __restrict__ A32,
    const ushort_t* __restrict__ Ahi, const ushort_t* __restrict__ Alo,
    const ushort_t* __restrict__ Bth, const ushort_t* __restrict__ Btl,
    const float* __restrict__ al, const float* __restrict__ ar,
    ushort_t* __restrict__ Cb, int ldc, int ncr,
    float* __restrict__ el, float* __restrict__ er)
{
    __shared__ uint4 smem[2048];    // A: [0:1024) hi, [1024:2048) lo  (32 KB)
    __shared__ uint4 smemB[2048];   // B: [0:1024) hi, [1024:2048) lo  (32 KB)

    const int tid  = threadIdx.x;
    const int wv   = tid >> 6;
    const int ln   = tid & 63;
    const int wm   = wv >> 1;          // 0..1 row-wave
    const int wn   = wv & 1;           // 0..1 col-wave
    const int cl   = ln & 15;
    const int kq   = ln >> 4;          // 0..3
    const int row0 = blockIdx.y * 128;
    const int col0 = blockIdx.x * 128;

    // B panel base for this block's 128 cols (4 k0-regions of 8192 elems)
    const ushort_t* bH = Bth + (size_t)blockIdx.x * 4 * 8192;
    const ushort_t* bL = Btl + (size_t)blockIdx.x * 4 * 8192;

    f32x4 acc[4][4] = {};

    for (int k0g = 0; k0g < 4; ++k0g) {
        const int k0 = k0g * 64;
        if (k0) __syncthreads();

        // ---- stage B region (linear copy, conflict-free by layout) -------
        {
            const ushort_t* rh = bH + k0g * 8192;
            const ushort_t* rl = bL + k0g * 8192;
            #pragma unroll
            for (int q = 0; q < 4; ++q) {
                int idx = q * 256 + tid;
                smemB[idx]        = *reinterpret_cast<const uint4*>(rh + idx * 8);
                smemB[1024 + idx] = *reinterpret_cast<const uint4*>(rl + idx * 8);
            }
        }

        // ---- stage A tile [128 rows][64 k] hi/lo, XOR-swizzled -----------
        if (AMODE == 1) {
            #pragma unroll
            for (int p = 0; p < 4; ++p) {
                int s = p * 256 + tid;
                int row = s >> 3, c = s & 7;
                int csw = c ^ (row & 7);
                size_t g = (size_t)(row0 + row) * 256 + k0 + c * 8;
                smem[row * 8 + csw]        = *reinterpret_cast<const uint4*>(Ahi + g);
                smem[1024 + row * 8 + csw] = *reinterpret_cast<const uint4*>(Alo + g);
            }
        } else {
            #pragma unroll
            for (int p = 0; p < 4; ++p) {
                int s = p * 256 + tid;
                int row = s >> 3, c = s & 7;
                int csw = c ^ (row & 7);
                int gr = row0 + row;
                float4 v0 = make_float4(0.f,0.f,0.f,0.f), v1 = v0;
                if (gr < NN) {
                    const float* g = A32 + (size_t)gr * 256 + k0 + c * 8;
                    v0 = *reinterpret_cast<const float4*>(g);
                    v1 = *reinterpret_cast<const float4*>(g + 4);
                }
                uint32_t b0 = __float_as_uint(v0.x), b1 = __float_as_uint(v0.y);
                uint32_t b2 = __float_as_uint(v0.z), b3 = __float_as_uint(v0.w);
                uint32_t b4 = __float_as_uint(v1.x), b5 = __float_as_uint(v1.y);
                uint32_t b6 = __float_as_uint(v1.z), b7 = __float_as_uint(v1.w);
                uint4 vh;
                vh.x = (b1 & 0xffff0000u) | (b0 >> 16);
                vh.y = (b3 & 0xffff0000u) | (b2 >> 16);
                vh.z = (b5 & 0xffff0000u) | (b4 >> 16);
                vh.w = (b7 & 0xffff0000u) | (b6 >> 16);
                float r0 = v0.x - __uint_as_float(b0 & 0xffff0000u);
                float r1 = v0.y - __uint_as_float(b1 & 0xffff0000u);
                float r2 = v0.z - __uint_as_float(b2 & 0xffff0000u);
                float r3 = v0.w - __uint_as_float(b3 & 0xffff0000u);
                float r4 = v1.x - __uint_as_float(b4 & 0xffff0000u);
                float r5 = v1.y - __uint_as_float(b5 & 0xffff0000u);
                float r6 = v1.z - __uint_as_float(b6 & 0xffff0000u);
                float r7 = v1.w - __uint_as_float(b7 & 0xffff0000u);
                uint4 vl;
                vl.x = (__float_as_uint(r1) & 0xffff0000u) | (__float_as_uint(r0) >> 16);
                vl.y = (__float_as_uint(r3) & 0xffff0000u) | (__float_as_uint(r2) >> 16);
                vl.z = (__float_as_uint(r5) & 0xffff0000u) | (__float_as_uint(r4) >> 16);
                vl.w = (__float_as_uint(r7) & 0xffff0000u) | (__float_as_uint(r6) >> 16);
                smem[row * 8 + csw]        = vh;
                smem[1024 + row * 8 + csw] = vl;
            }
        }
        __syncthreads();

        // ---- compute: 2 ksub windows of K=32, all operands from LDS ------
        #pragma unroll
        for (int ksub = 0; ksub < 2; ++ksub) {
            bf16x8 ah[4], ax[4];
            #pragma unroll
            for (int mf = 0; mf < 4; ++mf) {
                int row = wm * 64 + mf * 16 + cl;
                int chunk = (ksub * 4 + kq) ^ (row & 7);
                int idx = row * 8 + chunk;
                ah[mf] = ((const bf16x8*)smem)[idx];
                ax[mf] = ((const bf16x8*)smem)[1024 + idx];
            }
            #pragma unroll
            for (int nf = 0; nf < 4; ++nf) {
                int bidx = ((wn * 2 + ksub) * 4 + nf) * 64 + ln;
                bf16x8 bh = ((const bf16x8*)smemB)[bidx];
                bf16x8 bl = ((const bf16x8*)smemB)[1024 + bidx];
                #pragma unroll
                for (int mf = 0; mf < 4; ++mf) {
                    acc[mf][nf] = __builtin_amdgcn_mfma_f32_16x16x32_bf16(ah[mf], bh, acc[mf][nf], 0, 0, 0);
                    acc[mf][nf] = __builtin_amdgcn_mfma_f32_16x16x32_bf16(ah[mf], bl, acc[mf][nf], 0, 0, 0);
                    acc[mf][nf] = __builtin_amdgcn_mfma_f32_16x16x32_bf16(ax[mf], bh, acc[mf][nf], 0, 0, 0);
                }
            }
        }
    }

    // ---- epilogue: bf16 C store (+ fused scores) -------------------------
    #pragma unroll
    for (int mf = 0; mf < 4; ++mf) {
        int gr0 = row0 + wm * 64 + mf * 16 + kq * 4;
        #pragma unroll
        for (int r = 0; r < 4; ++r) {
            int gr = gr0 + r;
            if (gr < NN) {
                #pragma unroll
                for (int nf = 0; nf < 4; ++nf) {
                    int gc = col0 + wn * 64 + nf * 16 + cl;
                    if (gc < ncr)
                        Cb[(size_t)gr * ldc + gc] = f2bf_rn(acc[mf][nf][r]);
                }
            }
        }
    }

    if (DO_SCORES) {
        const int head = blockIdx.x * 2 + wn;
        float alv[4], arv[4];
        #pragma unroll
        for (int nf = 0; nf < 4; ++nf) {
            int d = nf * 16 + cl;
            alv[nf] = al[head * 64 + d];
            arv[nf] = ar[head * 64 + d];
        }
        #pragma unroll
        for (int mf = 0; mf < 4; ++mf) {
            #pragma unroll
            for (int r = 0; r < 4; ++r) {
                float pl = 0.f, pr = 0.f;
                #pragma unroll
                for (int nf = 0; nf < 4; ++nf) {
                    pl += acc[mf][nf][r] * alv[nf];
                    pr += acc[mf][nf][r] * arv[nf];
                }
                #pragma unroll
                for (int msk = 1; msk <= 8; msk <<= 1) {
                    pl += __shfl_xor(pl, msk);
                    pr += __shfl_xor(pr, msk);
                }
                if (cl == 0) {
                    int gr = row0 + wm * 64 + mf * 16 + kq * 4 + r;
                    if (gr < NN) {
                        el[gr * HEADS + head] = pl;
                        er[gr * HEADS + head] = pr;
                    }
                }
            }
        }
    }
}

// ---- layer-2 scores from bf16 feat (D=41, HD=164) --------------------------
__global__ __launch_bounds__(256) void scores2_bf(
    const ushort_t* __restrict__ featb, const float* __restrict__ al,
    const float* __restrict__ ar, float* __restrict__ el, float* __restrict__ er)
{
    const int n = blockIdx.x;
    const int t = threadIdx.x;
    const int h = t >> 6;
    const int j = t & 63;
    float v = 0.f, u = 0.f;
    if (j < 41) {
        float f = bf2f(featb[(size_t)n * 164 + h * 41 + j]);
        v = f * al[h * 41 + j];
        u = f * ar[h * 41 + j];
    }
    #pragma unroll
    for (int off = 32; off > 0; off >>= 1) {
        v += __shfl_down(v, off);
        u += __shfl_down(u, off);
    }
    if (j == 0) {
        el[n * HEADS + h] = v;
        er[n * HEADS + h] = u;
    }
}

// ---- aggregation (HD=256): wave per node; writes h as hi/lo split ----------
__global__ __launch_bounds__(256) void agg_full_bf(
    const ushort_t* __restrict__ featb, const float* __restrict__ el,
    const float* __restrict__ er, const int* __restrict__ col,
    ushort_t* __restrict__ Hhi, ushort_t* __restrict__ Hlo)
{
    __shared__ int   s_src[4][DEG];
    __shared__ float s_alpha[4][HEADS][DEG];

    const int t = threadIdx.x;
    const int w = t >> 6;
    const int l = t & 63;
    const int n = blockIdx.x * 4 + w;
    const int h = l >> 4;
    const int k = l & 15;

    const int src_k = col[n * DEG + k];
    float x = el[src_k * HEADS + h] + er[n * HEADS + h];
    x = x > 0.f ? x : NEG_SLOPE * x;

    float m = x;
    #pragma unroll
    for (int msk = 8; msk >= 1; msk >>= 1) m = fmaxf(m, __shfl_xor(m, msk));
    float ex = __expf(x - m);
    float s = ex;
    #pragma unroll
    for (int msk = 8; msk >= 1; msk >>= 1) s += __shfl_xor(s, msk);

    s_alpha[w][h][k] = ex / s;
    if (l < DEG) s_src[w][l] = src_k;
    __syncthreads();

    float4 acc = make_float4(0.f, 0.f, 0.f, 0.f);
    #pragma unroll
    for (int k2 = 0; k2 < DEG; ++k2) {
        const int   sk = s_src[w][k2];
        const float a  = s_alpha[w][h][k2];
        ushort4 f = *reinterpret_cast<const ushort4*>(&featb[(size_t)sk * 256 + l * 4]);
        acc.x += a * bf2f(f.x);
        acc.y += a * bf2f(f.y);
        acc.z += a * bf2f(f.z);
        acc.w += a * bf2f(f.w);
    }
    uint32_t bx = __float_as_uint(acc.x), by = __float_as_uint(acc.y);
    uint32_t bz = __float_as_uint(acc.z), bw = __float_as_uint(acc.w);
    ushort4 hv;
    hv.x = (ushort_t)(bx >> 16); hv.y = (ushort_t)(by >> 16);
    hv.z = (ushort_t)(bz >> 16); hv.w = (ushort_t)(bw >> 16);
    float rx = acc.x - __uint_as_float(bx & 0xffff0000u);
    float ry = acc.y - __uint_as_float(by & 0xffff0000u);
    float rz = acc.z - __uint_as_float(bz & 0xffff0000u);
    float rw = acc.w - __uint_as_float(bw & 0xffff0000u);
    ushort4 lv;
    lv.x = (ushort_t)(__float_as_uint(rx) >> 16);
    lv.y = (ushort_t)(__float_as_uint(ry) >> 16);
    lv.z = (ushort_t)(__float_as_uint(rz) >> 16);
    lv.w = (ushort_t)(__float_as_uint(rw) >> 16);
    *reinterpret_cast<ushort4*>(&Hhi[(size_t)n * 256 + l * 4]) = hv;
    *reinterpret_cast<ushort4*>(&Hlo[(size_t)n * 256 + l * 4]) = lv;
}

// ---- output-layer aggregation (HD=164, mean over heads) --------------------
__global__ __launch_bounds__(256) void agg_out_bf(
    const ushort_t* __restrict__ featb, const float* __restrict__ el,
    const float* __restrict__ er, const int* __restrict__ col,
    float* __restrict__ out)   // out: [N, 41]
{
    __shared__ int   s_src[4][DEG];
    __shared__ float s_alpha[4][HEADS][DEG];
    __shared__ float s_agg[4][164];

    const int t = threadIdx.x;
    const int w = t >> 6;
    const int l = t & 63;
    const int n = blockIdx.x * 4 + w;
    const int h = l >> 4;
    const int k = l & 15;

    const int src_k = col[n * DEG + k];
    float x = el[src_k * HEADS + h] + er[n * HEADS + h];
    x = x > 0.f ? x : NEG_SLOPE * x;

    float m = x;
    #pragma unroll
    for (int msk = 8; msk >= 1; msk >>= 1) m = fmaxf(m, __shfl_xor(m, msk));
    float ex = __expf(x - m);
    float s = ex;
    #pragma unroll
    for (int msk = 8; msk >= 1; msk >>= 1) s += __shfl_xor(s, msk);

    s_alpha[w][h][k] = ex / s;
    if (l < DEG) s_src[w][l] = src_k;
    __syncthreads();

    const int l41 = l < 41 ? l : 40;
    const int c0 = 4 * l41;
    const int h0 = (c0 + 0) / 41, h1 = (c0 + 1) / 41;
    const int h2 = (c0 + 2) / 41, h3 = (c0 + 3) / 41;

    float4 acc = make_float4(0.f, 0.f, 0.f, 0.f);
    #pragma unroll
    for (int k2 = 0; k2 < DEG; ++k2) {
        const int sk = s_src[w][k2];
        ushort4 f = *reinterpret_cast<const ushort4*>(&featb[(size_t)sk * 164 + c0]);
        acc.x += s_alpha[w][h0][k2] * bf2f(f.x);
        acc.y += s_alpha[w][h1][k2] * bf2f(f.y);
        acc.z += s_alpha[w][h2][k2] * bf2f(f.z);
        acc.w += s_alpha[w][h3][k2] * bf2f(f.w);
    }
    if (l < 41) *reinterpret_cast<float4*>(&s_agg[w][c0]) = acc;
    __syncthreads();
    if (l < 41)
        out[(size_t)n * 41 + l] =
            0.25f * (s_agg[w][l] + s_agg[w][l + 41] + s_agg[w][l + 82] + s_agg[w][l + 123]);
}

extern "C" void kernel_launch(void* const* d_in, const int* in_sizes, int n_in,
                              void* d_out, int out_size, void* d_ws, size_t ws_size,
                              hipStream_t stream)
{
    const int*   col_ind = (const int*)  d_in[1];
    const float* inputs  = (const float*)d_in[2];
    const float* W0      = (const float*)d_in[3];
    const float* al0     = (const float*)d_in[4];
    const float* ar0     = (const float*)d_in[5];
    const float* W1      = (const float*)d_in[6];
    const float* al1     = (const float*)d_in[7];
    const float* ar1     = (const float*)d_in[8];
    const float* W2      = (const float*)d_in[9];
    const float* al2     = (const float*)d_in[10];
    const float* ar2     = (const float*)d_in[11];
    float* out = (float*)d_out;

    char* ws = (char*)d_ws;
    const size_t seg = (size_t)NPAD * 256 * sizeof(ushort_t);   // 51.25 MB
    ushort_t* h_hi  = (ushort_t*)(ws);
    ushort_t* h_lo  = (ushort_t*)(ws + seg);
    ushort_t* featb = (ushort_t*)(ws + 2 * seg);
    float*    el    = (float*)(ws + 3 * seg);
    float*    er    = el + (size_t)NN * HEADS;
    ushort_t* wt    = (ushort_t*)(er + (size_t)NN * HEADS);
    ushort_t* wt0h = wt;              ushort_t* wt0l = wt + 65536;
    ushort_t* wt1h = wt + 2 * 65536;  ushort_t* wt1l = wt + 3 * 65536;
    ushort_t* wt2h = wt + 4 * 65536;  ushort_t* wt2l = wt + 5 * 65536;

    dim3 blk(256);
    dim3 gg(2, (NN + 127) / 128);
    const int waveGrid = NN / 4;

    prep_wt<<<256, blk, 0, stream>>>(W0, wt0h, wt0l, 256);
    prep_wt<<<256, blk, 0, stream>>>(W1, wt1h, wt1l, 256);
    prep_wt<<<256, blk, 0, stream>>>(W2, wt2h, wt2l, 164);

    // Layer 0: fp32 A path, fused scores
    gemm_mfma<0, true><<<gg, blk, 0, stream>>>(
        inputs, nullptr, nullptr, wt0h, wt0l, al0, ar0, featb, 256, 256, el, er);
    agg_full_bf<<<waveGrid, blk, 0, stream>>>(featb, el, er, col_ind, h_hi, h_lo);

    // Layer 1: presplit A path, fused scores
    gemm_mfma<1, true><<<gg, blk, 0, stream>>>(
        nullptr, h_hi, h_lo, wt1h, wt1l, al1, ar1, featb, 256, 256, el, er);
    agg_full_bf<<<waveGrid, blk, 0, stream>>>(featb, el, er, col_ind, h_hi, h_lo);

    // Layer 2: presplit A, no fused scores
    gemm_mfma<1, false><<<gg, blk, 0, stream>>>(
        nullptr, h_hi, h_lo, wt2h, wt2l, nullptr, nullptr, featb, 164, 164, nullptr, nullptr);
    scores2_bf<<<NN, blk, 0, stream>>>(featb, al2, ar2, el, er);
    agg_out_bf<<<waveGrid, blk, 0, stream>>>(featb, el, er, col_ind, out);
}

// Round 7
// 646.491 us; speedup vs baseline: 2.1089x; 1.0179x over previous
//
#include <hip/hip_runtime.h>

#define NN 100000
#define DEG 16
#define HEADS 4
#define NEG_SLOPE 0.2f
#define NPAD 100096   // 782 * 128

typedef unsigned short ushort_t;
typedef __attribute__((ext_vector_type(8))) short bf16x8;
typedef __attribute__((ext_vector_type(4))) float f32x4;

__device__ __forceinline__ ushort_t f2bf_rn(float f) {
    uint32_t u = __float_as_uint(f);
    uint32_t r = (u + 0x7fffu + ((u >> 16) & 1u)) >> 16;
    return (ushort_t)r;
}
__device__ __forceinline__ float bf2f(ushort_t u) {
    return __uint_as_float(((uint32_t)u) << 16);
}

// async 16B global->LDS DMA: LDS dest = wave-uniform base + lane*16
__device__ __forceinline__ void gld16(const void* g, void* l) {
    __builtin_amdgcn_global_load_lds(
        (const __attribute__((address_space(1))) unsigned int*)g,
        (__attribute__((address_space(3))) unsigned int*)l, 16, 0, 0);
}

// ---- prep: W[k][col] -> fragment-linear hi/lo bf16 panels ------------------
// Layout (16B chunks): [p][k0g][wn][ksub][nf][ln], chunk elem j:
//   col = p*128 + wn*64 + nf*16 + (ln&15)
//   k   = k0g*64 + ksub*32 + (ln>>4)*8 + j
__global__ __launch_bounds__(256) void prep_wt(
    const float* __restrict__ W, ushort_t* __restrict__ Wh,
    ushort_t* __restrict__ Wl, int ncr)
{
    int idx = blockIdx.x * 256 + threadIdx.x;   // 65536 elements
    int j     = idx & 7;
    int chunk = idx >> 3;
    int ln   = chunk & 63;
    int nf   = (chunk >> 6) & 3;
    int ksub = (chunk >> 8) & 1;
    int wn   = (chunk >> 9) & 1;
    int k0g  = (chunk >> 10) & 3;
    int p    = (chunk >> 12) & 1;
    int col = p * 128 + wn * 64 + nf * 16 + (ln & 15);
    int k   = k0g * 64 + ksub * 32 + (ln >> 4) * 8 + j;
    float v = (col < ncr) ? W[k * ncr + col] : 0.f;
    uint32_t b  = __float_as_uint(v);
    uint32_t hb = b & 0xffff0000u;
    float r = v - __uint_as_float(hb);
    Wh[idx] = (ushort_t)(hb >> 16);
    Wl[idx] = (ushort_t)(__float_as_uint(r) >> 16);
}

// ---- split-bf16 MFMA GEMM: C[M,256] = A[M,256] * W[256,256] ----------------
// AMODE 0: A = fp32 A32 (layer 0, reg-staged+split).  AMODE 1: presplit bf16,
// staged via global_load_lds (LDS linear dest, swizzle folded into source).
template <int AMODE, bool DO_SCORES>
__global__ __launch_bounds__(256) void gemm_mfma(
    const float* __restrict__ A32,
    const ushort_t* __restrict__ Ahi, const ushort_t* __restrict__ Alo,
    const ushort_t* __restrict__ Bth, const ushort_t* __restrict__ Btl,
    const float* __restrict__ al, const float* __restrict__ ar,
    ushort_t* __restrict__ Cb, int ldc, int ncr,
    float* __restrict__ el, float* __restrict__ er)
{
    __shared__ uint4 smem[2048];    // A: [0:1024) hi, [1024:2048) lo  (32 KB)
    __shared__ uint4 smemB[2048];   // B: [0:1024) hi, [1024:2048) lo  (32 KB)

    const int tid  = threadIdx.x;
    const int wv   = tid >> 6;
    const int ln   = tid & 63;
    const int wm   = wv >> 1;          // 0..1 row-wave
    const int wn   = wv & 1;           // 0..1 col-wave
    const int cl   = ln & 15;
    const int kq   = ln >> 4;          // 0..3
    const int row0 = blockIdx.y * 128;
    const int col0 = blockIdx.x * 128;

    // B panel base for this block's 128 cols (4 k0-regions of 8192 elems)
    const ushort_t* bH = Bth + (size_t)blockIdx.x * 4 * 8192;
    const ushort_t* bL = Btl + (size_t)blockIdx.x * 4 * 8192;

    f32x4 acc[4][4] = {};

    for (int k0g = 0; k0g < 4; ++k0g) {
        const int k0 = k0g * 64;
        if (k0) __syncthreads();

        // ---- stage B region: linear gload_lds copy (layout as R6) --------
        {
            const ushort_t* rh = bH + k0g * 8192;
            const ushort_t* rl = bL + k0g * 8192;
            #pragma unroll
            for (int q = 0; q < 4; ++q) {
                int i = wv * 4 + q;                 // wave-load block 0..15
                gld16(rh + (size_t)(i * 64 + ln) * 8, (char*)smemB + i * 1024);
                gld16(rl + (size_t)(i * 64 + ln) * 8, (char*)smemB + 16384 + i * 1024);
            }
        }

        // ---- stage A tile [128 rows][64 k] hi/lo -------------------------
        if (AMODE == 1) {
            // swizzle folded into source addr; LDS dest linear.
            // lane ln covers row rb*8+(ln>>3), slot ln&7, chunk c=(ln&7)^(ln>>3)
            const int rl8 = ln >> 3;
            const int c   = (ln & 7) ^ rl8;
            #pragma unroll
            for (int q = 0; q < 4; ++q) {
                int rb = wv * 4 + q;               // 8-row block 0..15
                size_t g = (size_t)(row0 + rb * 8 + rl8) * 256 + k0 + c * 8;
                gld16(Ahi + g, (char*)smem + rb * 1024);
                gld16(Alo + g, (char*)smem + 16384 + rb * 1024);
            }
        } else {
            #pragma unroll
            for (int p = 0; p < 4; ++p) {
                int s = p * 256 + tid;
                int row = s >> 3, c = s & 7;
                int csw = c ^ (row & 7);
                int gr = row0 + row;
                float4 v0 = make_float4(0.f,0.f,0.f,0.f), v1 = v0;
                if (gr < NN) {
                    const float* g = A32 + (size_t)gr * 256 + k0 + c * 8;
                    v0 = *reinterpret_cast<const float4*>(g);
                    v1 = *reinterpret_cast<const float4*>(g + 4);
                }
                uint32_t b0 = __float_as_uint(v0.x), b1 = __float_as_uint(v0.y);
                uint32_t b2 = __float_as_uint(v0.z), b3 = __float_as_uint(v0.w);
                uint32_t b4 = __float_as_uint(v1.x), b5 = __float_as_uint(v1.y);
                uint32_t b6 = __float_as_uint(v1.z), b7 = __float_as_uint(v1.w);
                uint4 vh;
                vh.x = (b1 & 0xffff0000u) | (b0 >> 16);
                vh.y = (b3 & 0xffff0000u) | (b2 >> 16);
                vh.z = (b5 & 0xffff0000u) | (b4 >> 16);
                vh.w = (b7 & 0xffff0000u) | (b6 >> 16);
                float r0 = v0.x - __uint_as_float(b0 & 0xffff0000u);
                float r1 = v0.y - __uint_as_float(b1 & 0xffff0000u);
                float r2 = v0.z - __uint_as_float(b2 & 0xffff0000u);
                float r3 = v0.w - __uint_as_float(b3 & 0xffff0000u);
                float r4 = v1.x - __uint_as_float(b4 & 0xffff0000u);
                float r5 = v1.y - __uint_as_float(b5 & 0xffff0000u);
                float r6 = v1.z - __uint_as_float(b6 & 0xffff0000u);
                float r7 = v1.w - __uint_as_float(b7 & 0xffff0000u);
                uint4 vl;
                vl.x = (__float_as_uint(r1) & 0xffff0000u) | (__float_as_uint(r0) >> 16);
                vl.y = (__float_as_uint(r3) & 0xffff0000u) | (__float_as_uint(r2) >> 16);
                vl.z = (__float_as_uint(r5) & 0xffff0000u) | (__float_as_uint(r4) >> 16);
                vl.w = (__float_as_uint(r7) & 0xffff0000u) | (__float_as_uint(r6) >> 16);
                smem[row * 8 + csw]        = vh;
                smem[1024 + row * 8 + csw] = vl;
            }
        }
        __syncthreads();   // compiler drains vmcnt+lgkmcnt before s_barrier

        // ---- compute: 2 ksub windows of K=32, all operands from LDS ------
        #pragma unroll
        for (int ksub = 0; ksub < 2; ++ksub) {
            bf16x8 ah[4], ax[4];
            #pragma unroll
            for (int mf = 0; mf < 4; ++mf) {
                int row = wm * 64 + mf * 16 + cl;
                int chunk = (ksub * 4 + kq) ^ (row & 7);
                int idx = row * 8 + chunk;
                ah[mf] = ((const bf16x8*)smem)[idx];
                ax[mf] = ((const bf16x8*)smem)[1024 + idx];
            }
            #pragma unroll
            for (int nf = 0; nf < 4; ++nf) {
                int bidx = ((wn * 2 + ksub) * 4 + nf) * 64 + ln;
                bf16x8 bh = ((const bf16x8*)smemB)[bidx];
                bf16x8 bl = ((const bf16x8*)smemB)[1024 + bidx];
                #pragma unroll
                for (int mf = 0; mf < 4; ++mf) {
                    acc[mf][nf] = __builtin_amdgcn_mfma_f32_16x16x32_bf16(ah[mf], bh, acc[mf][nf], 0, 0, 0);
                    acc[mf][nf] = __builtin_amdgcn_mfma_f32_16x16x32_bf16(ah[mf], bl, acc[mf][nf], 0, 0, 0);
                    acc[mf][nf] = __builtin_amdgcn_mfma_f32_16x16x32_bf16(ax[mf], bh, acc[mf][nf], 0, 0, 0);
                }
            }
        }
    }

    // ---- epilogue: bf16 C store (+ fused scores) -------------------------
    #pragma unroll
    for (int mf = 0; mf < 4; ++mf) {
        int gr0 = row0 + wm * 64 + mf * 16 + kq * 4;
        #pragma unroll
        for (int r = 0; r < 4; ++r) {
            int gr = gr0 + r;
            if (gr < NN) {
                #pragma unroll
                for (int nf = 0; nf < 4; ++nf) {
                    int gc = col0 + wn * 64 + nf * 16 + cl;
                    if (gc < ncr)
                        Cb[(size_t)gr * ldc + gc] = f2bf_rn(acc[mf][nf][r]);
                }
            }
        }
    }

    if (DO_SCORES) {
        const int head = blockIdx.x * 2 + wn;
        float alv[4], arv[4];
        #pragma unroll
        for (int nf = 0; nf < 4; ++nf) {
            int d = nf * 16 + cl;
            alv[nf] = al[head * 64 + d];
            arv[nf] = ar[head * 64 + d];
        }
        #pragma unroll
        for (int mf = 0; mf < 4; ++mf) {
            #pragma unroll
            for (int r = 0; r < 4; ++r) {
                float pl = 0.f, pr = 0.f;
                #pragma unroll
                for (int nf = 0; nf < 4; ++nf) {
                    pl += acc[mf][nf][r] * alv[nf];
                    pr += acc[mf][nf][r] * arv[nf];
                }
                #pragma unroll
                for (int msk = 1; msk <= 8; msk <<= 1) {
                    pl += __shfl_xor(pl, msk);
                    pr += __shfl_xor(pr, msk);
                }
                if (cl == 0) {
                    int gr = row0 + wm * 64 + mf * 16 + kq * 4 + r;
                    if (gr < NN) {
                        el[gr * HEADS + head] = pl;
                        er[gr * HEADS + head] = pr;
                    }
                }
            }
        }
    }
}

// ---- layer-2 scores from bf16 feat (D=41, HD=164) --------------------------
__global__ __launch_bounds__(256) void scores2_bf(
    const ushort_t* __restrict__ featb, const float* __restrict__ al,
    const float* __restrict__ ar, float* __restrict__ el, float* __restrict__ er)
{
    const int n = blockIdx.x;
    const int t = threadIdx.x;
    const int h = t >> 6;
    const int j = t & 63;
    float v = 0.f, u = 0.f;
    if (j < 41) {
        float f = bf2f(featb[(size_t)n * 164 + h * 41 + j]);
        v = f * al[h * 41 + j];
        u = f * ar[h * 41 + j];
    }
    #pragma unroll
    for (int off = 32; off > 0; off >>= 1) {
        v += __shfl_down(v, off);
        u += __shfl_down(u, off);
    }
    if (j == 0) {
        el[n * HEADS + h] = v;
        er[n * HEADS + h] = u;
    }
}

// ---- aggregation (HD=256): wave per node; writes h as hi/lo split ----------
__global__ __launch_bounds__(256) void agg_full_bf(
    const ushort_t* __restrict__ featb, const float* __restrict__ el,
    const float* __restrict__ er, const int* __restrict__ col,
    ushort_t* __restrict__ Hhi, ushort_t* __restrict__ Hlo)
{
    __shared__ int   s_src[4][DEG];
    __shared__ float s_alpha[4][HEADS][DEG];

    const int t = threadIdx.x;
    const int w = t >> 6;
    const int l = t & 63;
    const int n = blockIdx.x * 4 + w;
    const int h = l >> 4;
    const int k = l & 15;

    const int src_k = col[n * DEG + k];
    float x = el[src_k * HEADS + h] + er[n * HEADS + h];
    x = x > 0.f ? x : NEG_SLOPE * x;

    float m = x;
    #pragma unroll
    for (int msk = 8; msk >= 1; msk >>= 1) m = fmaxf(m, __shfl_xor(m, msk));
    float ex = __expf(x - m);
    float s = ex;
    #pragma unroll
    for (int msk = 8; msk >= 1; msk >>= 1) s += __shfl_xor(s, msk);

    s_alpha[w][h][k] = ex / s;
    if (l < DEG) s_src[w][l] = src_k;
    __syncthreads();

    float4 acc = make_float4(0.f, 0.f, 0.f, 0.f);
    #pragma unroll
    for (int k2 = 0; k2 < DEG; ++k2) {
        const int   sk = s_src[w][k2];
        const float a  = s_alpha[w][h][k2];
        ushort4 f = *reinterpret_cast<const ushort4*>(&featb[(size_t)sk * 256 + l * 4]);
        acc.x += a * bf2f(f.x);
        acc.y += a * bf2f(f.y);
        acc.z += a * bf2f(f.z);
        acc.w += a * bf2f(f.w);
    }
    uint32_t bx = __float_as_uint(acc.x), by = __float_as_uint(acc.y);
    uint32_t bz = __float_as_uint(acc.z), bw = __float_as_uint(acc.w);
    ushort4 hv;
    hv.x = (ushort_t)(bx >> 16); hv.y = (ushort_t)(by >> 16);
    hv.z = (ushort_t)(bz >> 16); hv.w = (ushort_t)(bw >> 16);
    float rx = acc.x - __uint_as_float(bx & 0xffff0000u);
    float ry = acc.y - __uint_as_float(by & 0xffff0000u);
    float rz = acc.z - __uint_as_float(bz & 0xffff0000u);
    float rw = acc.w - __uint_as_float(bw & 0xffff0000u);
    ushort4 lv;
    lv.x = (ushort_t)(__float_as_uint(rx) >> 16);
    lv.y = (ushort_t)(__float_as_uint(ry) >> 16);
    lv.z = (ushort_t)(__float_as_uint(rz) >> 16);
    lv.w = (ushort_t)(__float_as_uint(rw) >> 16);
    *reinterpret_cast<ushort4*>(&Hhi[(size_t)n * 256 + l * 4]) = hv;
    *reinterpret_cast<ushort4*>(&Hlo[(size_t)n * 256 + l * 4]) = lv;
}

// ---- output-layer aggregation (HD=164, mean over heads) --------------------
__global__ __launch_bounds__(256) void agg_out_bf(
    const ushort_t* __restrict__ featb, const float* __restrict__ el,
    const float* __restrict__ er, const int* __restrict__ col,
    float* __restrict__ out)   // out: [N, 41]
{
    __shared__ int   s_src[4][DEG];
    __shared__ float s_alpha[4][HEADS][DEG];
    __shared__ float s_agg[4][164];

    const int t = threadIdx.x;
    const int w = t >> 6;
    const int l = t & 63;
    const int n = blockIdx.x * 4 + w;
    const int h = l >> 4;
    const int k = l & 15;

    const int src_k = col[n * DEG + k];
    float x = el[src_k * HEADS + h] + er[n * HEADS + h];
    x = x > 0.f ? x : NEG_SLOPE * x;

    float m = x;
    #pragma unroll
    for (int msk = 8; msk >= 1; msk >>= 1) m = fmaxf(m, __shfl_xor(m, msk));
    float ex = __expf(x - m);
    float s = ex;
    #pragma unroll
    for (int msk = 8; msk >= 1; msk >>= 1) s += __shfl_xor(s, msk);

    s_alpha[w][h][k] = ex / s;
    if (l < DEG) s_src[w][l] = src_k;
    __syncthreads();

    const int l41 = l < 41 ? l : 40;
    const int c0 = 4 * l41;
    const int h0 = (c0 + 0) / 41, h1 = (c0 + 1) / 41;
    const int h2 = (c0 + 2) / 41, h3 = (c0 + 3) / 41;

    float4 acc = make_float4(0.f, 0.f, 0.f, 0.f);
    #pragma unroll
    for (int k2 = 0; k2 < DEG; ++k2) {
        const int sk = s_src[w][k2];
        ushort4 f = *reinterpret_cast<const ushort4*>(&featb[(size_t)sk * 164 + c0]);
        acc.x += s_alpha[w][h0][k2] * bf2f(f.x);
        acc.y += s_alpha[w][h1][k2] * bf2f(f.y);
        acc.z += s_alpha[w][h2][k2] * bf2f(f.z);
        acc.w += s_alpha[w][h3][k2] * bf2f(f.w);
    }
    if (l < 41) *reinterpret_cast<float4*>(&s_agg[w][c0]) = acc;
    __syncthreads();
    if (l < 41)
        out[(size_t)n * 41 + l] =
            0.25f * (s_agg[w][l] + s_agg[w][l + 41] + s_agg[w][l + 82] + s_agg[w][l + 123]);
}

extern "C" void kernel_launch(void* const* d_in, const int* in_sizes, int n_in,
                              void* d_out, int out_size, void* d_ws, size_t ws_size,
                              hipStream_t stream)
{
    const int*   col_ind = (const int*)  d_in[1];
    const float* inputs  = (const float*)d_in[2];
    const float* W0      = (const float*)d_in[3];
    const float* al0     = (const float*)d_in[4];
    const float* ar0     = (const float*)d_in[5];
    const float* W1      = (const float*)d_in[6];
    const float* al1     = (const float*)d_in[7];
    const float* ar1     = (const float*)d_in[8];
    const float* W2      = (const float*)d_in[9];
    const float* al2     = (const float*)d_in[10];
    const float* ar2     = (const float*)d_in[11];
    float* out = (float*)d_out;

    char* ws = (char*)d_ws;
    const size_t seg = (size_t)NPAD * 256 * sizeof(ushort_t);   // 51.25 MB
    ushort_t* h_hi  = (ushort_t*)(ws);
    ushort_t* h_lo  = (ushort_t*)(ws + seg);
    ushort_t* featb = (ushort_t*)(ws + 2 * seg);
    float*    el    = (float*)(ws + 3 * seg);
    float*    er    = el + (size_t)NN * HEADS;
    ushort_t* wt    = (ushort_t*)(er + (size_t)NN * HEADS);
    ushort_t* wt0h = wt;              ushort_t* wt0l = wt + 65536;
    ushort_t* wt1h = wt + 2 * 65536;  ushort_t* wt1l = wt + 3 * 65536;
    ushort_t* wt2h = wt + 4 * 65536;  ushort_t* wt2l = wt + 5 * 65536;

    dim3 blk(256);
    dim3 gg(2, (NN + 127) / 128);
    const int waveGrid = NN / 4;

    prep_wt<<<256, blk, 0, stream>>>(W0, wt0h, wt0l, 256);
    prep_wt<<<256, blk, 0, stream>>>(W1, wt1h, wt1l, 256);
    prep_wt<<<256, blk, 0, stream>>>(W2, wt2h, wt2l, 164);

    // Layer 0: fp32 A path, fused scores
    gemm_mfma<0, true><<<gg, blk, 0, stream>>>(
        inputs, nullptr, nullptr, wt0h, wt0l, al0, ar0, featb, 256, 256, el, er);
    agg_full_bf<<<waveGrid, blk, 0, stream>>>(featb, el, er, col_ind, h_hi, h_lo);

    // Layer 1: presplit A path, fused scores
    gemm_mfma<1, true><<<gg, blk, 0, stream>>>(
        nullptr, h_hi, h_lo, wt1h, wt1l, al1, ar1, featb, 256, 256, el, er);
    agg_full_bf<<<waveGrid, blk, 0, stream>>>(featb, el, er, col_ind, h_hi, h_lo);

    // Layer 2: presplit A, no fused scores
    gemm_mfma<1, false><<<gg, blk, 0, stream>>>(
        nullptr, h_hi, h_lo, wt2h, wt2l, nullptr, nullptr, featb, 164, 164, nullptr, nullptr);
    scores2_bf<<<NN, blk, 0, stream>>>(featb, al2, ar2, el, er);
    agg_out_bf<<<waveGrid, blk, 0, stream>>>(featb, el, er, col_ind, out);
}